// Round 13
// baseline (158.511 us; speedup 1.0000x reference)
//
#include <hip/hip_runtime.h>

#define NR 131072
#define DD 32
#define KK 64
#define BETA_C 10.0f
#define WROWS 256                    // rows per syrk worker
#define GRIDW 640                    // >= sum ceil(c_k/WROWS) <= 512+64 = 576
#define TRI(i, j) ((i) * ((i) + 1) / 2 + (j))
#define LSTR 44                      // LDS row stride (dwords): 16B-aligned,
                                     // 12r mod 32 -> 2-way max (free, m136)

// ---------------------------------------------------------------------------
// R20 = R15 pipeline (validated best 129.4) + phase1 v6: GEMM-tiled.
// Evidence: R17 (35 us/pass, scalar feed, no spill) + R19 (48 us, LDS feed,
// pv spill: WRITE 43MB) prove ANY per-thread stream of all 64 centers costs
// >=35 us. syrk (same dot shape) is fast because it register-tiles: 8 FMA
// per b128. v6 = syrk's pattern on phase1: block = 64 rows x 64 k; thread
// (rr=tid>>4, c=tid&15) owns rows {rr+16q} x k {c+16p} (4x4); per jc-chunk
// 8 broadcast b128 reads (4 x-rows + 4 c-rows) feed 64 FMAs. Per-thread LDS
// reads 512 -> 64; no pv array (16 d2 regs are the state) -> ~60 live regs,
// no spill. Stride-44 padding: x-reads conflict-free, c-reads 2-way (free).
// Exactness: dot/xx/cn ascending-j chains = validated; d2 formula identical;
// argmin = lexicographic (d2,k) min == first-index (reference semantics);
// softmax shift exp(B*(best-d2)) as validated. ssum/fill reduction TREES
// differ (R16 precedent: tree changes -> absmax 0.0). pred/hist exact.
//
// ws layout (float-indexed):
//   [0,64)   fill_g   [64,65) lossAcc   [67,68) doneF(int)
//   [128,192) hist_g (int)   [320,384) cursor (int)
//   [1824,35616) m2low_g (K x 528 tri)  [35616,37664) sums_g (K x 32)
//   [37664,70432) pred8 (uchar N)       [70432,+N) idx (uint N, 512 KB)
// memset zeroes [0,384) floats only; m2low/sums zeroed by scatter.
// ---------------------------------------------------------------------------

// phase 1 v6: 2048 blocks x 256 thr; 64-row tile x all 64 k per block.
__global__ __launch_bounds__(256, 2) void phase1_kernel(
    const float* __restrict__ x, const float* __restrict__ centers,
    float* __restrict__ fill_g, int* __restrict__ hist_g,
    unsigned char* __restrict__ pred_g) {
  __shared__ float xS[64][LSTR];   // x tile, 11 KB
  __shared__ float cS[64][LSTR];   // centers, 11 KB
  __shared__ float cnS[KK];
  __shared__ float xxS[64];
  __shared__ float fillW[4][KK];
  __shared__ int histS[KK];

  const int tid = threadIdx.x;
  const int lane = tid & 63;
  const int w = tid >> 6;
  const int c = tid & 15;          // k-group: owns k = c + 16p
  const int rr = tid >> 4;         // row-group: owns rows rr + 16q

  // stage x tile + centers (512 float4 each, coalesced, 2 per thread)
  {
    const float4* xg = (const float4*)(x + (size_t)blockIdx.x * 64 * DD);
    const float4* cg = (const float4*)centers;
    const int f0 = tid, f1 = tid + 256;
    *(float4*)&xS[f0 >> 3][(f0 & 7) * 4] = xg[f0];
    *(float4*)&cS[f0 >> 3][(f0 & 7) * 4] = cg[f0];
    *(float4*)&xS[f1 >> 3][(f1 & 7) * 4] = xg[f1];
    *(float4*)&cS[f1 >> 3][(f1 & 7) * 4] = cg[f1];
    if (tid < KK) histS[tid] = 0;
  }
  __syncthreads();
  if (tid < KK) {
    float s = 0.f;
#pragma unroll
    for (int jc = 0; jc < 8; ++jc) {  // ascending j, validated chain (R19)
      const float4 cv = *(const float4*)&cS[tid][jc * 4];
      s += cv.x * cv.x;
      s += cv.y * cv.y;
      s += cv.z * cv.z;
      s += cv.w * cv.w;
    }
    cnS[tid] = s;
    float t = 0.f;
#pragma unroll
    for (int jc = 0; jc < 8; ++jc) {  // ascending j == validated xx chain
      const float4 xv = *(const float4*)&xS[tid][jc * 4];
      t += xv.x * xv.x;
      t += xv.y * xv.y;
      t += xv.z * xv.z;
      t += xv.w * xv.w;
    }
    xxS[tid] = t;
  }
  __syncthreads();

  // row/center base pointers -> ds_read_b128 with imm offsets
  const float* xrow0 = &xS[rr + 0][0];
  const float* xrow1 = &xS[rr + 16][0];
  const float* xrow2 = &xS[rr + 32][0];
  const float* xrow3 = &xS[rr + 48][0];
  const float* crow0 = &cS[c + 0][0];
  const float* crow1 = &cS[c + 16][0];
  const float* crow2 = &cS[c + 32][0];
  const float* crow3 = &cS[c + 48][0];

  float cc[4][4];
#pragma unroll
  for (int q = 0; q < 4; ++q)
#pragma unroll
    for (int p = 0; p < 4; ++p) cc[q][p] = 0.f;

#pragma unroll
  for (int jc = 0; jc < 8; ++jc) {
    float4 xa[4], cb[4];
    xa[0] = *(const float4*)(xrow0 + jc * 4);
    xa[1] = *(const float4*)(xrow1 + jc * 4);
    xa[2] = *(const float4*)(xrow2 + jc * 4);
    xa[3] = *(const float4*)(xrow3 + jc * 4);
    cb[0] = *(const float4*)(crow0 + jc * 4);
    cb[1] = *(const float4*)(crow1 + jc * 4);
    cb[2] = *(const float4*)(crow2 + jc * 4);
    cb[3] = *(const float4*)(crow3 + jc * 4);
#pragma unroll
    for (int q = 0; q < 4; ++q)
#pragma unroll
      for (int p = 0; p < 4; ++p) {  // ascending-j serial chain per (row,k)
        cc[q][p] += xa[q].x * cb[p].x;
        cc[q][p] += xa[q].y * cb[p].y;
        cc[q][p] += xa[q].z * cb[p].z;
        cc[q][p] += xa[q].w * cb[p].w;
      }
  }

  const float cn0 = cnS[c + 0], cn1 = cnS[c + 16];
  const float cn2 = cnS[c + 32], cn3 = cnS[c + 48];

  float fpart[4] = {0.f, 0.f, 0.f, 0.f};
#pragma unroll
  for (int q = 0; q < 4; ++q) {
    const float xxv = xxS[rr + 16 * q];
    const float d0 = xxv - 2.0f * cc[q][0] + cn0;  // validated d2 formula
    const float d1 = xxv - 2.0f * cc[q][1] + cn1;
    const float d2_ = xxv - 2.0f * cc[q][2] + cn2;
    const float d3 = xxv - 2.0f * cc[q][3] + cn3;

    // thread-local argmin, ascending p (k ascending for fixed c)
    float best = d0;
    int bk = c;
    if (d1 < best) { best = d1; bk = c + 16; }
    if (d2_ < best) { best = d2_; bk = c + 32; }
    if (d3 < best) { best = d3; bk = c + 48; }
    // cross-lane (c bits 0..3): lexicographic (d2,k) min == first-index ties
#pragma unroll
    for (int m = 1; m <= 8; m <<= 1) {
      const float ob = __shfl_xor(best, m, 64);
      const int obk = __shfl_xor(bk, m, 64);
      if (ob < best || (ob == best && obk < bk)) { best = ob; bk = obk; }
    }
    if (c == 0) {
      const int row = blockIdx.x * 64 + rr + 16 * q;
      pred_g[row] = (unsigned char)bk;
      atomicAdd(&histS[bk], 1);
    }

    // shifted softmax (validated form)
    const float e0 = __expf(BETA_C * (best - d0));
    const float e1 = __expf(BETA_C * (best - d1));
    const float e2 = __expf(BETA_C * (best - d2_));
    const float e3 = __expf(BETA_C * (best - d3));
    float s = ((e0 + e1) + e2) + e3;
#pragma unroll
    for (int m = 1; m <= 8; m <<= 1) s += __shfl_xor(s, m, 64);
    const float inv = 1.0f / s;
    fpart[0] += e0 * inv;  // row-sum per k, ascending q
    fpart[1] += e1 * inv;
    fpart[2] += e2 * inv;
    fpart[3] += e3 * inv;
  }

  // sum the 4 row-groups within the wave (lane bits 4..5)
#pragma unroll
  for (int p = 0; p < 4; ++p) {
    fpart[p] += __shfl_xor(fpart[p], 16, 64);
    fpart[p] += __shfl_xor(fpart[p], 32, 64);
  }
  if (lane < 16) {  // lane == c for these lanes
#pragma unroll
    for (int p = 0; p < 4; ++p) fillW[w][c + 16 * p] = fpart[p];
  }
  __syncthreads();
  if (tid < KK) {
    atomicAdd(&fill_g[tid],
              fillW[0][tid] + fillW[1][tid] + fillW[2][tid] + fillW[3][tid]);
    if (histS[tid]) atomicAdd(&hist_g[tid], histS[tid]);
  }
}

// scatter v3 (R15 verbatim, validated): counting-sort of ROW INDICES;
// self-plans segment bases via in-block scan of hist_g; zeroes m2low/sums.
__global__ __launch_bounds__(256) void scatter_kernel(
    const unsigned char* __restrict__ pred_g, const int* __restrict__ hist_g,
    int* __restrict__ cursor, unsigned int* __restrict__ idxg,
    float4* __restrict__ m2zero) {
  __shared__ int histS[KK];
  __shared__ int baseS[KK];

  const int tid = threadIdx.x;
  if (tid < 18) {  // zero m2low_g + sums_g: 35840 floats = 8960 float4
    const int z = blockIdx.x * 18 + tid;
    if (z < 8960) m2zero[z] = make_float4(0.f, 0.f, 0.f, 0.f);
  }
  if (tid < KK) histS[tid] = 0;
  __syncthreads();

  const int row = blockIdx.x * 256 + tid;
  const int bi = pred_g[row];
  const int rank = atomicAdd(&histS[bi], 1);
  __syncthreads();
  if (tid < KK) {  // threads 0..63 == wave 0: shuffle-scan is safe
    const int c = hist_g[tid];
    int inc = c;
#pragma unroll
    for (int off = 1; off < 64; off <<= 1) {
      const int v = __shfl_up(inc, off, 64);
      if (tid >= off) inc += v;
    }
    const int seg = inc - c;  // exclusive scan == segStart[tid]
    const int h = histS[tid];
    baseS[tid] = seg + (h ? atomicAdd(&cursor[tid], h) : 0);
  }
  __syncthreads();
  idxg[baseS[bi] + rank] = (unsigned int)row;  // ~4-row runs per cluster
}

// syrk v5 (R15 verbatim, validated): self-planning worker; gather via index
// list into transposed LDS tile; 4 wave-groups x 4x4 register tiles; LDS
// reduction; triangular flush.
__global__ __launch_bounds__(256) void syrk_kernel(
    const float* __restrict__ x, const unsigned int* __restrict__ idxg,
    const int* __restrict__ hist_g, float* __restrict__ m2low_g,
    float* __restrict__ sums_g) {
  __shared__ float xsT[DD][68];    // transposed tile, 8.7 KB (rows of 17 f4)
  __shared__ float red[4][64][16]; // per-group 4x4-tile partials, 16 KB
  __shared__ float sdred[4][DD];   // per-group row sums, 0.5 KB
  __shared__ int planS[3];         // k, base, cnt

  const int tid = threadIdx.x;
  if (tid < 64) {  // wave 0: derive this block's worker assignment
    const int c = hist_g[tid];
    int inc = c;
#pragma unroll
    for (int off = 1; off < 64; off <<= 1) {
      const int v = __shfl_up(inc, off, 64);
      if (tid >= off) inc += v;
    }
    const int seg = inc - c;
    const int nw = (c + WROWS - 1) / WROWS;
    int winc = nw;
#pragma unroll
    for (int off = 1; off < 64; off <<= 1) {
      const int v = __shfl_up(winc, off, 64);
      if (tid >= off) winc += v;
    }
    const int woff = winc - nw;
    const int wtot = __shfl(winc, 63, 64);  // total workers <= 576
    const int b = blockIdx.x;
    if (b >= wtot) {
      if (tid == 0) planS[0] = 255;
    } else if (b >= woff && b < woff + nw) {  // exactly one lane
      const int wi = b - woff;
      planS[0] = tid;
      planS[1] = seg + wi * WROWS;
      planS[2] = min(WROWS, c - wi * WROWS);
    }
  }
  __syncthreads();
  const int k = planS[0];
  if (k == 255) return;  // uniform exit after barrier
  const int base = planS[1];
  const int total = planS[2];

  const int grp = tid >> 6;   // 4 groups == 4 waves
  const int t6 = tid & 63;
  const int ti = t6 >> 3;     // 0..7: output rows i = ti + 8r, r=0..3
  const int tj = t6 & 7;      // 0..7: output cols j = tj + 8c, c=0..3

  float cc[4][4];
#pragma unroll
  for (int r = 0; r < 4; ++r)
#pragma unroll
    for (int c2 = 0; c2 < 4; ++c2) cc[r][c2] = 0.f;
  float sd[4] = {0.f, 0.f, 0.f, 0.f};

  const float4* xf4 = (const float4*)x;
  const int rl0 = tid >> 3;       // row-local for pass 0 (0..31)
  const int pt = tid & 7;         // float4 slot within row

  for (int off = 0; off < total; off += 64) {
    const int cnt = min(64, total - off);
    const int cnt4 = (cnt + 3) & ~3;
    __syncthreads();  // previous tile's readers done before overwrite

    if (rl0 < cnt) {
      const unsigned int r0 = idxg[base + off + rl0];
      const float4 v = xf4[(size_t)r0 * 8 + pt];
      xsT[pt * 4 + 0][rl0] = v.x;
      xsT[pt * 4 + 1][rl0] = v.y;
      xsT[pt * 4 + 2][rl0] = v.z;
      xsT[pt * 4 + 3][rl0] = v.w;
    }
    const int rl1 = rl0 + 32;
    if (rl1 < cnt) {
      const unsigned int r1 = idxg[base + off + rl1];
      const float4 v = xf4[(size_t)r1 * 8 + pt];
      xsT[pt * 4 + 0][rl1] = v.x;
      xsT[pt * 4 + 1][rl1] = v.y;
      xsT[pt * 4 + 2][rl1] = v.z;
      xsT[pt * 4 + 3][rl1] = v.w;
    }
    for (int e = cnt * DD + tid; e < cnt4 * DD; e += 256)
      xsT[e & 31][e >> 5] = 0.f;  // zero-pad rows to multiple of 4
    __syncthreads();

    const int gmax = cnt4 >> 2;
    for (int g = grp; g < gmax; g += 4) {  // row-quads strided by group
      float4 Af[4], Bf[4];
#pragma unroll
      for (int r = 0; r < 4; ++r)
        Af[r] = *(const float4*)&xsT[ti + 8 * r][4 * g];
#pragma unroll
      for (int c2 = 0; c2 < 4; ++c2)
        Bf[c2] = *(const float4*)&xsT[tj + 8 * c2][4 * g];
#pragma unroll
      for (int r = 0; r < 4; ++r)
#pragma unroll
        for (int c2 = 0; c2 < 4; ++c2)
          cc[r][c2] += Af[r].x * Bf[c2].x + Af[r].y * Bf[c2].y +
                       Af[r].z * Bf[c2].z + Af[r].w * Bf[c2].w;
      if (tj == 0) {
#pragma unroll
        for (int r = 0; r < 4; ++r)
          sd[r] += Af[r].x + Af[r].y + Af[r].z + Af[r].w;
      }
    }
  }

  // cross-group reduction through LDS, then triangular flush
#pragma unroll
  for (int r = 0; r < 4; ++r)
    *(float4*)&red[grp][t6][r * 4] =
        make_float4(cc[r][0], cc[r][1], cc[r][2], cc[r][3]);
  if (tj == 0) {
#pragma unroll
    for (int r = 0; r < 4; ++r) sdred[grp][ti + 8 * r] = sd[r];
  }
  __syncthreads();

  float* m2k = m2low_g + k * 528;
  {
    const int t6r = tid >> 2;        // which 4x4 tile (0..63)
    const int rr = tid & 3;          // which row of that tile
    const int tir = t6r >> 3, tjr = t6r & 7;
    const int i = tir + 8 * rr;
    float4 v0 = *(const float4*)&red[0][t6r][rr * 4];
    const float4 v1 = *(const float4*)&red[1][t6r][rr * 4];
    const float4 v2 = *(const float4*)&red[2][t6r][rr * 4];
    const float4 v3 = *(const float4*)&red[3][t6r][rr * 4];
    v0.x += v1.x + v2.x + v3.x;
    v0.y += v1.y + v2.y + v3.y;
    v0.z += v1.z + v2.z + v3.z;
    v0.w += v1.w + v2.w + v3.w;
    const float vv[4] = {v0.x, v0.y, v0.z, v0.w};
#pragma unroll
    for (int q = 0; q < 4; ++q) {
      const int j = tjr + 8 * q;
      if (j <= i) atomicAdd(&m2k[TRI(i, j)], vv[q]);
    }
  }
  if (tid < DD) {
    const float s =
        sdred[0][tid] + sdred[1][tid] + sdred[2][tid] + sdred[3][tid];
    atomicAdd(&sums_g[k * DD + tid], s);
  }
}

// finalize (R15 verbatim, validated): one block per cluster; last-arriving
// block writes the output scalar (fence only at pipeline END).
__global__ __launch_bounds__(256) void finalize_kernel(
    const float* __restrict__ fill_g, const int* __restrict__ hist_g,
    const float* __restrict__ sums_g, const float* __restrict__ m2low_g,
    const float* __restrict__ ft, const float* __restrict__ mt,
    const float* __restrict__ ct, float* __restrict__ lossAcc,
    int* __restrict__ doneF, float* __restrict__ out) {
  __shared__ float meanS[DD];
  __shared__ float wred[4];
  const int t = threadIdx.x;
  const int k = blockIdx.x;

  const float inv = 1.0f / fmaxf((float)hist_g[k], 1.0f);
  if (t < DD) meanS[t] = sums_g[k * DD + t] * inv;
  __syncthreads();

  float acc = 0.f;
  if (t < DD) {
    const float d = meanS[t] - mt[k * DD + t];
    acc += d * d * (1.0f / (KK * DD));
  }
  if (t == 0) {
    const float f = fill_g[k] * (1.0f / (float)NR) - ft[k];
    acc += f * f * (1.0f / KK);
  }
  const float* m2k = m2low_g + k * 528;
  const float* ctk = ct + k * (DD * DD);
#pragma unroll
  for (int u = 0; u < 4; ++u) {
    const int e = t + 256 * u;
    const int i = e >> 5, j = e & 31;
    const int idx = (i >= j) ? TRI(i, j) : TRI(j, i);
    const float cov = m2k[idx] * inv - meanS[i] * meanS[j];
    const float d = cov - ctk[e];
    acc += d * d * (1.0f / (KK * DD * DD));
  }

  acc += __shfl_xor(acc, 32, 64);
  acc += __shfl_xor(acc, 16, 64);
  acc += __shfl_xor(acc, 8, 64);
  acc += __shfl_xor(acc, 4, 64);
  acc += __shfl_xor(acc, 2, 64);
  acc += __shfl_xor(acc, 1, 64);
  if ((t & 63) == 0) wred[t >> 6] = acc;
  __syncthreads();
  if (t == 0) {
    atomicAdd(lossAcc, wred[0] + wred[1] + wred[2] + wred[3]);
    __threadfence();  // release: lossAcc visible before doneF bump
    if (atomicAdd(doneF, 1) == KK - 1) {
      out[0] = atomicAdd(lossAcc, 0.0f);  // coherent-path read
    }
  }
}

extern "C" void kernel_launch(void* const* d_in, const int* in_sizes, int n_in,
                              void* d_out, int out_size, void* d_ws,
                              size_t ws_size, hipStream_t stream) {
  (void)in_sizes; (void)n_in; (void)out_size; (void)ws_size;
  const float* x = (const float*)d_in[0];
  const float* centers = (const float*)d_in[1];
  const float* ft = (const float*)d_in[2];
  const float* mt = (const float*)d_in[3];
  const float* ct = (const float*)d_in[4];
  float* out = (float*)d_out;

  float* ws = (float*)d_ws;
  float* fill_g = ws;                                   // 64
  float* lossAcc = ws + 64;                             // 1
  int* doneF = (int*)(ws + 67);                         // 1
  int* hist_g = (int*)(ws + 128);                       // 64
  int* cursor = (int*)(ws + 320);                       // 64
  float* m2low_g = ws + 1824;                           // 33792
  float* sums_g = ws + 35616;                           // 2048
  unsigned char* pred8 = (unsigned char*)(ws + 37664);  // N bytes
  unsigned int* idxg = (unsigned int*)(ws + 70432);     // N uints (512 KB)

  // zero fill_g/lossAcc/doneF/hist/cursor only (1.5 KB); m2low/sums are
  // zeroed inside scatter (stream-ordered ahead of syrk's atomics).
  hipMemsetAsync(d_ws, 0, (size_t)384 * sizeof(float), stream);

  phase1_kernel<<<NR / 64, 256, 0, stream>>>(x, centers, fill_g, hist_g,
                                             pred8);
  scatter_kernel<<<NR / 256, 256, 0, stream>>>(pred8, hist_g, cursor, idxg,
                                               (float4*)m2low_g);
  syrk_kernel<<<GRIDW, 256, 0, stream>>>(x, idxg, hist_g, m2low_g, sums_g);
  finalize_kernel<<<KK, 256, 0, stream>>>(fill_g, hist_g, sums_g, m2low_g, ft,
                                          mt, ct, lossAcc, doneF, out);
}

// Round 14
// 129.272 us; speedup vs baseline: 1.2262x; 1.2262x over previous
//
#include <hip/hip_runtime.h>

#define NR 131072
#define DD 32
#define KK 64
#define BETA_C 10.0f
#define WROWS 256                    // rows per syrk worker
#define GRIDW 640                    // >= sum ceil(c_k/WROWS) <= 512+64 = 576
#define TRI(i, j) ((i) * ((i) + 1) / 2 + (j))

// ---------------------------------------------------------------------------
// R21 == R15 verbatim restore (session best, measured 129.4 us).
// Final-round decision: seven phase1 restructurings (R12-R14, R16-R20)
// attacked spills/ILP/occupancy/scalar-feed/LDS-feed/register-tiling; all
// landed >= the R12 form's ~36 us. Pre-committed decision rules (R18, R20)
// both fired: revert to validated best and declare the practical floor.
// Budget: ~42 us harness poison-fill (fixed) + ~36 us phase1 (structural)
// + ~25 us scatter/syrk/finalize + launch gaps.
//
// R15 = R12 + dispatch-count reduction 7 -> 4, fence-free on hot paths:
//   (1) planner removed: scatter re-derives the hist scan in-block; syrk
//       wave0 self-plans its (k, base, cnt) from hist_g.
//   (2) finalizeB fused into finalizeA (last-block pattern, fence only at
//       pipeline END).
//   (3) memset shrunk to 1.5 KB; m2low/sums zeroed inside scatter.
//
// ws layout (float-indexed):
//   [0,64)   fill_g   [64,65) lossAcc   [67,68) doneF(int)
//   [128,192) hist_g (int)   [320,384) cursor (int)
//   [1824,35616) m2low_g (K x 528 tri)  [35616,37664) sums_g (K x 32)
//   [37664,70432) pred8 (uchar N)       [70432,+N) idx (uint N, 512 KB)
// memset zeroes [0,384) floats only; m2low/sums zeroed by scatter.
// ---------------------------------------------------------------------------

// phase 1 (R12 verbatim, measured-best): one row/thread, centers via
// wave-uniform s_load path, 63-shuffle transpose-reduce, block histogram.
__global__ __launch_bounds__(256, 2) void phase1_kernel(
    const float* __restrict__ x, const float* __restrict__ centers,
    float* __restrict__ fill_g, int* __restrict__ hist_g,
    unsigned char* __restrict__ pred_g) {
  __shared__ float cnS[KK];
  __shared__ float fillW[4][KK];
  __shared__ int histS[KK];

  const int tid = threadIdx.x;
  const int lane = tid & 63;
  const int wid = tid >> 6;

  if (tid < KK) {
    float s = 0.f;
    const float* cp = centers + tid * DD;
#pragma unroll
    for (int j = 0; j < DD; ++j) s += cp[j] * cp[j];
    cnS[tid] = s;
    histS[tid] = 0;
  }
  __syncthreads();

  const int row = blockIdx.x * 256 + tid;  // grid == NR/256 exactly

  float xr[DD];
  const float4* xp = (const float4*)(x + (size_t)row * DD);
#pragma unroll
  for (int j = 0; j < 8; ++j) {
    const float4 v = xp[j];
    xr[4 * j + 0] = v.x;
    xr[4 * j + 1] = v.y;
    xr[4 * j + 2] = v.z;
    xr[4 * j + 3] = v.w;
  }
  float xx = 0.f;
#pragma unroll
  for (int j = 0; j < DD; ++j) xx += xr[j] * xr[j];

  float pv[KK];
  float best = 3.4e38f;
  int bi = 0;
#pragma unroll
  for (int k = 0; k < KK; ++k) {
    float dot = 0.f;
#pragma unroll
    for (int j = 0; j < DD; ++j)
      dot += xr[j] * centers[k * DD + j];  // uniform addr -> s_load (K$)
    const float d2 = xx - 2.0f * dot + cnS[k];
    pv[k] = d2;
    if (d2 < best) { best = d2; bi = k; }  // strict < == first-index ties
  }
  pred_g[row] = (unsigned char)bi;
  atomicAdd(&histS[bi], 1);

  float ssum = 0.f;
#pragma unroll
  for (int k = 0; k < KK; ++k) {
    const float e = __expf(BETA_C * (best - pv[k]));
    pv[k] = e;
    ssum += e;
  }
  const float inv = 1.0f / ssum;
#pragma unroll
  for (int k = 0; k < KK; ++k) pv[k] *= inv;

#pragma unroll
  for (int m = 32; m >= 1; m >>= 1) {
    const bool hi = (lane & m) != 0;
#pragma unroll
    for (int i = 0; i < m; ++i) {
      const float send = hi ? pv[i] : pv[i + m];
      const float recv = __shfl_xor(send, m, 64);
      const float keep = hi ? pv[i + m] : pv[i];
      pv[i] = keep + recv;
    }
  }
  fillW[wid][lane] = pv[0];
  __syncthreads();
  if (tid < KK) {
    atomicAdd(&fill_g[tid],
              fillW[0][tid] + fillW[1][tid] + fillW[2][tid] + fillW[3][tid]);
    if (histS[tid]) atomicAdd(&hist_g[tid], histS[tid]);
  }
}

// scatter v3 (validated): counting-sort of ROW INDICES; self-plans the
// cluster segment bases via an in-block scan of hist_g (cursor zero-based ->
// values identical to the validated planner path). Also zeroes m2low_g+
// sums_g (8960 float4 across 512 blocks; stream-ordered ahead of syrk).
__global__ __launch_bounds__(256) void scatter_kernel(
    const unsigned char* __restrict__ pred_g, const int* __restrict__ hist_g,
    int* __restrict__ cursor, unsigned int* __restrict__ idxg,
    float4* __restrict__ m2zero) {
  __shared__ int histS[KK];
  __shared__ int baseS[KK];

  const int tid = threadIdx.x;
  if (tid < 18) {  // zero m2low_g + sums_g: 35840 floats = 8960 float4
    const int z = blockIdx.x * 18 + tid;
    if (z < 8960) m2zero[z] = make_float4(0.f, 0.f, 0.f, 0.f);
  }
  if (tid < KK) histS[tid] = 0;
  __syncthreads();

  const int row = blockIdx.x * 256 + tid;
  const int bi = pred_g[row];
  const int rank = atomicAdd(&histS[bi], 1);
  __syncthreads();
  if (tid < KK) {  // threads 0..63 == wave 0: shuffle-scan is safe
    const int c = hist_g[tid];
    int inc = c;
#pragma unroll
    for (int off = 1; off < 64; off <<= 1) {
      const int v = __shfl_up(inc, off, 64);
      if (tid >= off) inc += v;
    }
    const int seg = inc - c;  // exclusive scan == segStart[tid]
    const int h = histS[tid];
    baseS[tid] = seg + (h ? atomicAdd(&cursor[tid], h) : 0);
  }
  __syncthreads();
  idxg[baseS[bi] + rank] = (unsigned int)row;  // ~4-row runs per cluster
}

// syrk v5 (validated): self-planning worker = (cluster k, <=256 rows via
// index list). Wave 0 scans hist_g, finds the worker interval containing
// blockIdx, and broadcasts (k, base, cnt). Compute core = validated syrk v4.
__global__ __launch_bounds__(256) void syrk_kernel(
    const float* __restrict__ x, const unsigned int* __restrict__ idxg,
    const int* __restrict__ hist_g, float* __restrict__ m2low_g,
    float* __restrict__ sums_g) {
  __shared__ float xsT[DD][68];    // transposed tile, 8.7 KB (rows of 17 f4)
  __shared__ float red[4][64][16]; // per-group 4x4-tile partials, 16 KB
  __shared__ float sdred[4][DD];   // per-group row sums, 0.5 KB
  __shared__ int planS[3];         // k, base, cnt

  const int tid = threadIdx.x;
  if (tid < 64) {  // wave 0: derive this block's worker assignment
    const int c = hist_g[tid];
    int inc = c;
#pragma unroll
    for (int off = 1; off < 64; off <<= 1) {
      const int v = __shfl_up(inc, off, 64);
      if (tid >= off) inc += v;
    }
    const int seg = inc - c;
    const int nw = (c + WROWS - 1) / WROWS;
    int winc = nw;
#pragma unroll
    for (int off = 1; off < 64; off <<= 1) {
      const int v = __shfl_up(winc, off, 64);
      if (tid >= off) winc += v;
    }
    const int woff = winc - nw;
    const int wtot = __shfl(winc, 63, 64);  // total workers <= 576
    const int b = blockIdx.x;
    if (b >= wtot) {
      if (tid == 0) planS[0] = 255;
    } else if (b >= woff && b < woff + nw) {  // exactly one lane
      const int wi = b - woff;
      planS[0] = tid;
      planS[1] = seg + wi * WROWS;
      planS[2] = min(WROWS, c - wi * WROWS);
    }
  }
  __syncthreads();
  const int k = planS[0];
  if (k == 255) return;  // uniform exit after barrier
  const int base = planS[1];
  const int total = planS[2];

  const int grp = tid >> 6;   // 4 groups == 4 waves
  const int t6 = tid & 63;
  const int ti = t6 >> 3;     // 0..7: output rows i = ti + 8r, r=0..3
  const int tj = t6 & 7;      // 0..7: output cols j = tj + 8c, c=0..3

  float cc[4][4];
#pragma unroll
  for (int r = 0; r < 4; ++r)
#pragma unroll
    for (int c2 = 0; c2 < 4; ++c2) cc[r][c2] = 0.f;
  float sd[4] = {0.f, 0.f, 0.f, 0.f};

  const float4* xf4 = (const float4*)x;
  const int rl0 = tid >> 3;       // row-local for pass 0 (0..31)
  const int pt = tid & 7;         // float4 slot within row

  for (int off = 0; off < total; off += 64) {
    const int cnt = min(64, total - off);
    const int cnt4 = (cnt + 3) & ~3;
    __syncthreads();  // previous tile's readers done before overwrite

    if (rl0 < cnt) {
      const unsigned int r0 = idxg[base + off + rl0];
      const float4 v = xf4[(size_t)r0 * 8 + pt];
      xsT[pt * 4 + 0][rl0] = v.x;
      xsT[pt * 4 + 1][rl0] = v.y;
      xsT[pt * 4 + 2][rl0] = v.z;
      xsT[pt * 4 + 3][rl0] = v.w;
    }
    const int rl1 = rl0 + 32;
    if (rl1 < cnt) {
      const unsigned int r1 = idxg[base + off + rl1];
      const float4 v = xf4[(size_t)r1 * 8 + pt];
      xsT[pt * 4 + 0][rl1] = v.x;
      xsT[pt * 4 + 1][rl1] = v.y;
      xsT[pt * 4 + 2][rl1] = v.z;
      xsT[pt * 4 + 3][rl1] = v.w;
    }
    for (int e = cnt * DD + tid; e < cnt4 * DD; e += 256)
      xsT[e & 31][e >> 5] = 0.f;  // zero-pad rows to multiple of 4
    __syncthreads();

    const int gmax = cnt4 >> 2;
    for (int g = grp; g < gmax; g += 4) {  // row-quads strided by group
      float4 Af[4], Bf[4];
#pragma unroll
      for (int r = 0; r < 4; ++r)
        Af[r] = *(const float4*)&xsT[ti + 8 * r][4 * g];
#pragma unroll
      for (int c2 = 0; c2 < 4; ++c2)
        Bf[c2] = *(const float4*)&xsT[tj + 8 * c2][4 * g];
#pragma unroll
      for (int r = 0; r < 4; ++r)
#pragma unroll
        for (int c2 = 0; c2 < 4; ++c2)
          cc[r][c2] += Af[r].x * Bf[c2].x + Af[r].y * Bf[c2].y +
                       Af[r].z * Bf[c2].z + Af[r].w * Bf[c2].w;
      if (tj == 0) {
#pragma unroll
        for (int r = 0; r < 4; ++r)
          sd[r] += Af[r].x + Af[r].y + Af[r].z + Af[r].w;
      }
    }
  }

  // cross-group reduction through LDS, then triangular flush
#pragma unroll
  for (int r = 0; r < 4; ++r)
    *(float4*)&red[grp][t6][r * 4] =
        make_float4(cc[r][0], cc[r][1], cc[r][2], cc[r][3]);
  if (tj == 0) {
#pragma unroll
    for (int r = 0; r < 4; ++r) sdred[grp][ti + 8 * r] = sd[r];
  }
  __syncthreads();

  float* m2k = m2low_g + k * 528;
  {
    const int t6r = tid >> 2;        // which 4x4 tile (0..63)
    const int rr = tid & 3;          // which row of that tile
    const int tir = t6r >> 3, tjr = t6r & 7;
    const int i = tir + 8 * rr;
    float4 v0 = *(const float4*)&red[0][t6r][rr * 4];
    const float4 v1 = *(const float4*)&red[1][t6r][rr * 4];
    const float4 v2 = *(const float4*)&red[2][t6r][rr * 4];
    const float4 v3 = *(const float4*)&red[3][t6r][rr * 4];
    v0.x += v1.x + v2.x + v3.x;
    v0.y += v1.y + v2.y + v3.y;
    v0.z += v1.z + v2.z + v3.z;
    v0.w += v1.w + v2.w + v3.w;
    const float vv[4] = {v0.x, v0.y, v0.z, v0.w};
#pragma unroll
    for (int q = 0; q < 4; ++q) {
      const int j = tjr + 8 * q;
      if (j <= i) atomicAdd(&m2k[TRI(i, j)], vv[q]);
    }
  }
  if (tid < DD) {
    const float s =
        sdred[0][tid] + sdred[1][tid] + sdred[2][tid] + sdred[3][tid];
    atomicAdd(&sums_g[k * DD + tid], s);
  }
}

// finalize (validated): one block per cluster; last-arriving block writes
// the output scalar (fence only at pipeline END, nothing runs after).
__global__ __launch_bounds__(256) void finalize_kernel(
    const float* __restrict__ fill_g, const int* __restrict__ hist_g,
    const float* __restrict__ sums_g, const float* __restrict__ m2low_g,
    const float* __restrict__ ft, const float* __restrict__ mt,
    const float* __restrict__ ct, float* __restrict__ lossAcc,
    int* __restrict__ doneF, float* __restrict__ out) {
  __shared__ float meanS[DD];
  __shared__ float wred[4];
  const int t = threadIdx.x;
  const int k = blockIdx.x;

  const float inv = 1.0f / fmaxf((float)hist_g[k], 1.0f);
  if (t < DD) meanS[t] = sums_g[k * DD + t] * inv;
  __syncthreads();

  float acc = 0.f;
  if (t < DD) {
    const float d = meanS[t] - mt[k * DD + t];
    acc += d * d * (1.0f / (KK * DD));
  }
  if (t == 0) {
    const float f = fill_g[k] * (1.0f / (float)NR) - ft[k];
    acc += f * f * (1.0f / KK);
  }
  const float* m2k = m2low_g + k * 528;
  const float* ctk = ct + k * (DD * DD);
#pragma unroll
  for (int u = 0; u < 4; ++u) {
    const int e = t + 256 * u;
    const int i = e >> 5, j = e & 31;
    const int idx = (i >= j) ? TRI(i, j) : TRI(j, i);
    const float cov = m2k[idx] * inv - meanS[i] * meanS[j];
    const float d = cov - ctk[e];
    acc += d * d * (1.0f / (KK * DD * DD));
  }

  acc += __shfl_xor(acc, 32, 64);
  acc += __shfl_xor(acc, 16, 64);
  acc += __shfl_xor(acc, 8, 64);
  acc += __shfl_xor(acc, 4, 64);
  acc += __shfl_xor(acc, 2, 64);
  acc += __shfl_xor(acc, 1, 64);
  if ((t & 63) == 0) wred[t >> 6] = acc;
  __syncthreads();
  if (t == 0) {
    atomicAdd(lossAcc, wred[0] + wred[1] + wred[2] + wred[3]);
    __threadfence();  // release: lossAcc visible before doneF bump
    if (atomicAdd(doneF, 1) == KK - 1) {
      out[0] = atomicAdd(lossAcc, 0.0f);  // coherent-path read
    }
  }
}

extern "C" void kernel_launch(void* const* d_in, const int* in_sizes, int n_in,
                              void* d_out, int out_size, void* d_ws,
                              size_t ws_size, hipStream_t stream) {
  (void)in_sizes; (void)n_in; (void)out_size; (void)ws_size;
  const float* x = (const float*)d_in[0];
  const float* centers = (const float*)d_in[1];
  const float* ft = (const float*)d_in[2];
  const float* mt = (const float*)d_in[3];
  const float* ct = (const float*)d_in[4];
  float* out = (float*)d_out;

  float* ws = (float*)d_ws;
  float* fill_g = ws;                                   // 64
  float* lossAcc = ws + 64;                             // 1
  int* doneF = (int*)(ws + 67);                         // 1
  int* hist_g = (int*)(ws + 128);                       // 64
  int* cursor = (int*)(ws + 320);                       // 64
  float* m2low_g = ws + 1824;                           // 33792
  float* sums_g = ws + 35616;                           // 2048
  unsigned char* pred8 = (unsigned char*)(ws + 37664);  // N bytes
  unsigned int* idxg = (unsigned int*)(ws + 70432);     // N uints (512 KB)

  // zero fill_g/lossAcc/doneF/hist/cursor only (1.5 KB); m2low/sums are
  // zeroed inside scatter (stream-ordered ahead of syrk's atomics).
  hipMemsetAsync(d_ws, 0, (size_t)384 * sizeof(float), stream);

  phase1_kernel<<<NR / 256, 256, 0, stream>>>(x, centers, fill_g, hist_g,
                                              pred8);
  scatter_kernel<<<NR / 256, 256, 0, stream>>>(pred8, hist_g, cursor, idxg,
                                               (float4*)m2low_g);
  syrk_kernel<<<GRIDW, 256, 0, stream>>>(x, idxg, hist_g, m2low_g, sums_g);
  finalize_kernel<<<KK, 256, 0, stream>>>(fill_g, hist_g, sums_g, m2low_g, ft,
                                          mt, ct, lossAcc, doneF, out);
}